// Round 1
// baseline (166.824 us; speedup 1.0000x reference)
//
#include <hip/hip_runtime.h>
#include <math.h>

// feat: (N=4, C3=147, H=64, W=64) fp32
// out:  (N=4, 3, h=256, w=256) fp32
// c = 49 = 7*7, MAX_FREQ=3, OMEGA=pi/2

#define FH 64
#define FW 64
#define NC3 147
#define OH 256
#define OW 256

__device__ __forceinline__ void embed7(float r, float e[7]) {
    const float F1  = 1.5707963705062866f;  // float32(0.5*pi)
    const float SQ2 = 1.4142135381698608f;  // float32(sqrt(2))
    float a = r * F1;
    float s1 = __sinf(a);
    float c1 = __cosf(a);
    float s2 = 2.0f * s1 * c1;
    float c2 = c1 * c1 - s1 * s1;
    float s3 = s2 * c1 + c2 * s1;
    float c3 = c2 * c1 - s2 * s1;
    e[0] = 1.0f;
    e[1] = SQ2 * c1; e[2] = SQ2 * s1;
    e[3] = SQ2 * c2; e[4] = SQ2 * s2;
    e[5] = SQ2 * c3; e[6] = SQ2 * s3;
}

__global__ __launch_bounds__(256) void ope_render_kernel(
    const float* __restrict__ feat,
    const int* __restrict__ pflip1,
    const int* __restrict__ pflip3,
    float* __restrict__ out)
{
    const int j = threadIdx.x;   // w index 0..255
    const int i = blockIdx.x;    // h index 0..255
    const int n = blockIdx.y;    // batch 0..3
    const int flip1 = pflip1[0];
    const int flip3 = pflip3[0];

    // cell-center coords in [-1,1]; channel0 over h-axis
    float cx = -1.0f + (2.0f * (float)i + 1.0f) * (1.0f / 256.0f);
    float cy = -1.0f + (2.0f * (float)j + 1.0f) * (1.0f / 256.0f);
    if (flip1 == 1)      { cy = -cy; }
    else if (flip1 == 2) { cx = -cx; }
    else if (flip1 == 4) { cx = -cx; cy = -cy; }

    const float SH[2] = { (float)(-1.0 / 64.0 + 1e-6),   // vx/vy = -1
                          (float)( 1.0 / 64.0 + 1e-6) }; // vx/vy = +1
    const float CLO = (float)(-1.0 + 1e-6);
    const float CHI = (float)( 1.0 - 1e-6);

    float rel0[2], rel1[2];
    int   ihx[2], iwy[2];
    #pragma unroll
    for (int d = 0; d < 2; ++d) {
        // h-axis
        float c0 = fminf(fmaxf(cx + SH[d], CLO), CHI);
        int ih = (int)rintf(((c0 + 1.0f) * 64.0f - 1.0f) * 0.5f);  // round-half-even
        ih = min(max(ih, 0), FH - 1);
        ihx[d] = ih;
        float qh = -1.0f + (2.0f * (float)ih + 1.0f) * (1.0f / 64.0f);
        rel0[d] = (cx - qh) * 64.0f;
        // w-axis
        float c1 = fminf(fmaxf(cy + SH[d], CLO), CHI);
        int iw = (int)rintf(((c1 + 1.0f) * 64.0f - 1.0f) * 0.5f);
        iw = min(max(iw, 0), FW - 1);
        iwy[d] = iw;
        float qw = -1.0f + (2.0f * (float)iw + 1.0f) * (1.0f / 64.0f);
        rel1[d] = (cy - qw) * 64.0f;
    }

    // areas (abs -> flip3 sign irrelevant); s in order (vx,vy)=(-,-),(-,+),(+,-),(+,+)
    float a00 = fabsf(rel0[0] * rel1[0]) + 1e-9f;
    float a01 = fabsf(rel0[0] * rel1[1]) + 1e-9f;
    float a10 = fabsf(rel0[1] * rel1[0]) + 1e-9f;
    float a11 = fabsf(rel0[1] * rel1[1]) + 1e-9f;
    float tot = ((a00 + a01) + a10) + a11;
    // diagonal swap: pred_s weighted by area_{3-s}
    const float wgt[4] = { a11 / tot, a10 / tot, a01 / tot, a00 / tot };

    // flip3 applied to rel before embedding
    float r0f[2] = { rel0[0], rel0[1] };
    float r1f[2] = { rel1[0], rel1[1] };
    if (flip3 == 1)      { r1f[0] = -r1f[0]; r1f[1] = -r1f[1]; }
    else if (flip3 == 2) { r0f[0] = -r0f[0]; r0f[1] = -r0f[1]; }
    else if (flip3 == 4) { r0f[0] = -r0f[0]; r0f[1] = -r0f[1];
                           r1f[0] = -r1f[0]; r1f[1] = -r1f[1]; }

    float ex[2][7], ey[2][7];
    embed7(r0f[0], ex[0]); embed7(r0f[1], ex[1]);
    embed7(r1f[0], ey[0]); embed7(r1f[1], ey[1]);

    float acc0 = 0.0f, acc1 = 0.0f, acc2 = 0.0f;
    const float* __restrict__ fn = feat + (size_t)n * NC3 * FH * FW;

    #pragma unroll
    for (int s = 0; s < 4; ++s) {
        const int dx = s >> 1;  // vx dir
        const int dy = s & 1;   // vy dir
        const float* __restrict__ bp = fn + (size_t)ihx[dx] * FW + iwy[dy];
        float p0 = 0.0f, p1 = 0.0f, p2 = 0.0f;
        #pragma unroll
        for (int a = 0; a < 7; ++a) {
            const float ea = ex[dx][a];
            #pragma unroll
            for (int b = 0; b < 7; ++b) {
                const float o = ea * ey[dy][b];
                const int cc = a * 7 + b;
                p0 = fmaf(o, bp[(size_t)(cc      ) * (FH * FW)], p0);
                p1 = fmaf(o, bp[(size_t)(cc + 49 ) * (FH * FW)], p1);
                p2 = fmaf(o, bp[(size_t)(cc + 98 ) * (FH * FW)], p2);
            }
        }
        const float w = wgt[s];
        acc0 = fmaf(p0, w, acc0);
        acc1 = fmaf(p1, w, acc1);
        acc2 = fmaf(p2, w, acc2);
    }

    // out[n][k][i][j]
    const size_t ob = (size_t)n * 3 * OH * OW + (size_t)i * OW + (size_t)j;
    out[ob              ] = acc0;
    out[ob +     OH * OW] = acc1;
    out[ob + 2 * OH * OW] = acc2;
}

extern "C" void kernel_launch(void* const* d_in, const int* in_sizes, int n_in,
                              void* d_out, int out_size, void* d_ws, size_t ws_size,
                              hipStream_t stream) {
    const float* feat  = (const float*)d_in[0];
    const int*   flip1 = (const int*)d_in[3];
    const int*   flip3 = (const int*)d_in[4];
    float*       out   = (float*)d_out;

    dim3 grid(OH, 4);   // (h rows, batch)
    dim3 block(OW);     // w columns
    hipLaunchKernelGGL(ope_render_kernel, grid, block, 0, stream,
                       feat, flip1, flip3, out);
}

// Round 2
// 28.490 us; speedup vs baseline: 5.8556x; 5.8556x over previous
//
#include <hip/hip_runtime.h>
#include <math.h>

// feat: (N=4, C3=147, H=64, W=64) fp32
// out:  (N=4, 3, h=256, w=256) fp32
// c = 49 = 7*7, MAX_FREQ=3, OMEGA=pi/2

#define FH 64
#define FW 64
#define NC3 147
#define OH 256
#define OW 256

__device__ __forceinline__ void embed7(float r, float e[7]) {
    const float F1  = 1.5707963705062866f;  // float32(0.5*pi)
    const float SQ2 = 1.4142135381698608f;  // float32(sqrt(2))
    float a = r * F1;
    float s1 = __sinf(a);
    float c1 = __cosf(a);
    float s2 = 2.0f * s1 * c1;
    float c2 = c1 * c1 - s1 * s1;
    float s3 = s2 * c1 + c2 * s1;
    float c3 = c2 * c1 - s2 * s1;
    e[0] = 1.0f;
    e[1] = SQ2 * c1; e[2] = SQ2 * s1;
    e[3] = SQ2 * c2; e[4] = SQ2 * s2;
    e[5] = SQ2 * c3; e[6] = SQ2 * s3;
}

// One block per (n, i): stages the two needed feat rows (ih for both shift
// dirs, block-uniform) for all 147 channels into LDS, then each thread does
// its 4-corner 7x7x3 weighted dot from LDS.
__global__ __launch_bounds__(256) void ope_render_kernel(
    const float* __restrict__ feat,
    const int* __restrict__ pflip1,
    const int* __restrict__ pflip3,
    float* __restrict__ out)
{
    __shared__ float lds[2 * NC3 * FW];   // [dx][cc][iw] : 75264 B

    const int tid = threadIdx.x;
    const int i = blockIdx.x;    // h index 0..255
    const int n = blockIdx.y;    // batch 0..3
    const int flip1 = pflip1[0];
    const int flip3 = pflip3[0];

    // cell-center coords in [-1,1]; channel0 over h-axis
    float cx = -1.0f + (2.0f * (float)i + 1.0f) * (1.0f / 256.0f);
    float cy = -1.0f + (2.0f * (float)tid + 1.0f) * (1.0f / 256.0f);
    if (flip1 == 1)      { cy = -cy; }
    else if (flip1 == 2) { cx = -cx; }
    else if (flip1 == 4) { cx = -cx; cy = -cy; }

    const float SH[2] = { (float)(-1.0 / 64.0 + 1e-6),   // dir = -1
                          (float)( 1.0 / 64.0 + 1e-6) }; // dir = +1
    const float CLO = (float)(-1.0 + 1e-6);
    const float CHI = (float)( 1.0 - 1e-6);

    // h-axis (block-uniform) and w-axis (per-thread) nearest indices + rel
    float rel0[2], rel1[2];
    int   ihx[2], iwy[2];
    #pragma unroll
    for (int d = 0; d < 2; ++d) {
        float c0 = fminf(fmaxf(cx + SH[d], CLO), CHI);
        int ih = (int)rintf(((c0 + 1.0f) * 64.0f - 1.0f) * 0.5f);  // round-half-even
        ih = min(max(ih, 0), FH - 1);
        ihx[d] = ih;
        float qh = -1.0f + (2.0f * (float)ih + 1.0f) * (1.0f / 64.0f);
        rel0[d] = (cx - qh) * 64.0f;

        float c1 = fminf(fmaxf(cy + SH[d], CLO), CHI);
        int iw = (int)rintf(((c1 + 1.0f) * 64.0f - 1.0f) * 0.5f);
        iw = min(max(iw, 0), FW - 1);
        iwy[d] = iw;
        float qw = -1.0f + (2.0f * (float)iw + 1.0f) * (1.0f / 64.0f);
        rel1[d] = (cy - qw) * 64.0f;
    }

    // ---- cooperative stage: 2 rows x 147 channels x 64 cols ----
    {
        const float* __restrict__ fn = feat + (size_t)n * NC3 * FH * FW;
        const int total = 2 * NC3 * FW;            // 18816
        #pragma unroll
        for (int k = 0; k < 74; ++k) {             // ceil(18816/256)
            int t = tid + k * 256;
            if (t < total) {
                int col = t & (FW - 1);
                int r   = t >> 6;                  // 0..293
                int dxr = (r >= NC3) ? 1 : 0;
                int cc  = r - dxr * NC3;
                lds[t] = fn[(size_t)cc * (FH * FW) + (size_t)ihx[dxr] * FW + col];
            }
        }
    }
    __syncthreads();

    // areas (abs of rel products); s in order (vx,vy)=(-,-),(-,+),(+,-),(+,+)
    float a00 = fabsf(rel0[0] * rel1[0]) + 1e-9f;
    float a01 = fabsf(rel0[0] * rel1[1]) + 1e-9f;
    float a10 = fabsf(rel0[1] * rel1[0]) + 1e-9f;
    float a11 = fabsf(rel0[1] * rel1[1]) + 1e-9f;
    float tot = ((a00 + a01) + a10) + a11;
    // diagonal swap: pred_s weighted by area_{3-s}
    const float wgt0 = a11 / tot, wgt1 = a10 / tot, wgt2 = a01 / tot, wgt3 = a00 / tot;
    const float wgt[4] = { wgt0, wgt1, wgt2, wgt3 };

    // flip3 applied to rel before embedding
    float r0f[2] = { rel0[0], rel0[1] };
    float r1f[2] = { rel1[0], rel1[1] };
    if (flip3 == 1)      { r1f[0] = -r1f[0]; r1f[1] = -r1f[1]; }
    else if (flip3 == 2) { r0f[0] = -r0f[0]; r0f[1] = -r0f[1]; }
    else if (flip3 == 4) { r0f[0] = -r0f[0]; r0f[1] = -r0f[1];
                           r1f[0] = -r1f[0]; r1f[1] = -r1f[1]; }

    float ex[2][7], ey[2][7];
    embed7(r0f[0], ex[0]); embed7(r0f[1], ex[1]);
    embed7(r1f[0], ey[0]); embed7(r1f[1], ey[1]);

    float acc0 = 0.0f, acc1 = 0.0f, acc2 = 0.0f;

    #pragma unroll
    for (int s = 0; s < 4; ++s) {
        const int dx = s >> 1;  // vx dir
        const int dy = s & 1;   // vy dir
        const float* __restrict__ lp = &lds[dx * (NC3 * FW) + iwy[dy]];
        float p0 = 0.0f, p1 = 0.0f, p2 = 0.0f;
        #pragma unroll
        for (int a = 0; a < 7; ++a) {
            const float ea = ex[dx][a];
            #pragma unroll
            for (int b = 0; b < 7; ++b) {
                const float o = ea * ey[dy][b];
                const int cc = a * 7 + b;
                p0 = fmaf(o, lp[(cc      ) * FW], p0);
                p1 = fmaf(o, lp[(cc + 49 ) * FW], p1);
                p2 = fmaf(o, lp[(cc + 98 ) * FW], p2);
            }
        }
        const float w = wgt[s];
        acc0 = fmaf(p0, w, acc0);
        acc1 = fmaf(p1, w, acc1);
        acc2 = fmaf(p2, w, acc2);
    }

    // out[n][k][i][j]
    const size_t ob = (size_t)n * 3 * OH * OW + (size_t)i * OW + (size_t)tid;
    out[ob              ] = acc0;
    out[ob +     OH * OW] = acc1;
    out[ob + 2 * OH * OW] = acc2;
}

extern "C" void kernel_launch(void* const* d_in, const int* in_sizes, int n_in,
                              void* d_out, int out_size, void* d_ws, size_t ws_size,
                              hipStream_t stream) {
    const float* feat  = (const float*)d_in[0];
    const int*   flip1 = (const int*)d_in[3];
    const int*   flip3 = (const int*)d_in[4];
    float*       out   = (float*)d_out;

    dim3 grid(OH, 4);   // (h rows, batch)
    dim3 block(OW);     // w columns
    hipLaunchKernelGGL(ope_render_kernel, grid, block, 0, stream,
                       feat, flip1, flip3, out);
}

// Round 3
// 27.852 us; speedup vs baseline: 5.9897x; 1.0229x over previous
//
#include <hip/hip_runtime.h>
#include <math.h>

// feat: (N=4, C3=147, H=64, W=64) fp32
// out:  (N=4, 3, h=256, w=256) fp32
// c = 49 = 7*7, MAX_FREQ=3, OMEGA=pi/2

#define FH 64
#define FW 64
#define NC3 147
#define OH 256
#define OW 256
#define CST 148          // channel stride in LDS (147 + 1 pad, 16B-aligned: 148*4=592)
#define NG  37           // float4 groups per (dir,col): 148/4

__device__ __forceinline__ void embed7(float r, float e[7]) {
    const float F1  = 1.5707963705062866f;  // float32(0.5*pi)
    const float SQ2 = 1.4142135381698608f;  // float32(sqrt(2))
    float a = r * F1;
    float s1 = __sinf(a);
    float c1 = __cosf(a);
    float s2 = 2.0f * s1 * c1;
    float c2 = c1 * c1 - s1 * s1;
    float s3 = s2 * c1 + c2 * s1;
    float c3 = c2 * c1 - s2 * s1;
    e[0] = 1.0f;
    e[1] = SQ2 * c1; e[2] = SQ2 * s1;
    e[3] = SQ2 * c2; e[4] = SQ2 * s2;
    e[5] = SQ2 * c3; e[6] = SQ2 * s3;
}

// One block per (n, i). LDS holds the two needed feat rows transposed to
// [dir][col][channel] so each (corner,col)'s 147 channels are contiguous and
// read via ds_read_b128 (4x fewer LDS instructions than b32).
__global__ __launch_bounds__(256) void ope_render_kernel(
    const float* __restrict__ feat,
    const int* __restrict__ pflip1,
    const int* __restrict__ pflip3,
    float* __restrict__ out)
{
    __shared__ float lds[2 * FW * CST];   // 2*64*148*4B = 75776 B

    const int tid = threadIdx.x;
    // XCD-aware bijective remap: 1024 blocks, 8 XCDs round-robin on bid%8.
    // XCD x owns n = x>>1 and i-range (x&1)*128 .. +127  -> each XCD's L2
    // only sees ~1/8 of feat's rows.
    const int bid  = blockIdx.x;           // 0..1023
    const int xcd  = bid & 7;
    const int idx  = bid >> 3;             // 0..127
    const int n    = xcd >> 1;             // 0..3
    const int i    = ((xcd & 1) << 7) + idx;  // 0..255
    const int flip1 = pflip1[0];
    const int flip3 = pflip3[0];

    float cx = -1.0f + (2.0f * (float)i + 1.0f) * (1.0f / 256.0f);
    float cy = -1.0f + (2.0f * (float)tid + 1.0f) * (1.0f / 256.0f);
    if (flip1 == 1)      { cy = -cy; }
    else if (flip1 == 2) { cx = -cx; }
    else if (flip1 == 4) { cx = -cx; cy = -cy; }

    const float SH[2] = { (float)(-1.0 / 64.0 + 1e-6),
                          (float)( 1.0 / 64.0 + 1e-6) };
    const float CLO = (float)(-1.0 + 1e-6);
    const float CHI = (float)( 1.0 - 1e-6);

    float rel0[2], rel1[2];
    int   ihx[2], iwy[2];
    #pragma unroll
    for (int d = 0; d < 2; ++d) {
        float c0 = fminf(fmaxf(cx + SH[d], CLO), CHI);
        int ih = (int)rintf(((c0 + 1.0f) * 64.0f - 1.0f) * 0.5f);  // round-half-even
        ih = min(max(ih, 0), FH - 1);
        ihx[d] = ih;
        float qh = -1.0f + (2.0f * (float)ih + 1.0f) * (1.0f / 64.0f);
        rel0[d] = (cx - qh) * 64.0f;

        float c1 = fminf(fmaxf(cy + SH[d], CLO), CHI);
        int iw = (int)rintf(((c1 + 1.0f) * 64.0f - 1.0f) * 0.5f);
        iw = min(max(iw, 0), FW - 1);
        iwy[d] = iw;
        float qw = -1.0f + (2.0f * (float)iw + 1.0f) * (1.0f / 64.0f);
        rel1[d] = (cy - qw) * 64.0f;
    }

    // ---- cooperative transpose-stage ----
    // 4736 float4 units: (dir 2) x (col 64) x (group 37). Each thread loads
    // 4 channels (coalesced across col) and writes one ds_write_b128.
    {
        const float* __restrict__ fn = feat + (size_t)n * NC3 * FH * FW;
        #pragma unroll
        for (int k = 0; k < 19; ++k) {            // ceil(4736/256)
            int t = tid + k * 256;
            if (t < 2 * FW * NG) {
                int dxr = (t >= FW * NG) ? 1 : 0;
                int tt  = t - dxr * (FW * NG);
                int g   = tt >> 6;                // 0..36
                int col = tt & 63;
                const float* __restrict__ src =
                    fn + (size_t)(4 * g) * (FH * FW) + (size_t)ihx[dxr] * FW + col;
                float4 v;
                v.x = src[0];
                v.y = src[FH * FW];
                v.z = src[2 * FH * FW];
                v.w = (4 * g + 3 < NC3) ? src[3 * FH * FW] : 0.0f;
                *(float4*)(&lds[(size_t)dxr * (FW * CST) + (size_t)col * CST + 4 * g]) = v;
            }
        }
    }
    __syncthreads();

    // areas; s order (vx,vy)=(-,-),(-,+),(+,-),(+,+)
    float a00 = fabsf(rel0[0] * rel1[0]) + 1e-9f;
    float a01 = fabsf(rel0[0] * rel1[1]) + 1e-9f;
    float a10 = fabsf(rel0[1] * rel1[0]) + 1e-9f;
    float a11 = fabsf(rel0[1] * rel1[1]) + 1e-9f;
    float tot = ((a00 + a01) + a10) + a11;
    const float wgt[4] = { a11 / tot, a10 / tot, a01 / tot, a00 / tot };  // diagonal swap

    float r0f[2] = { rel0[0], rel0[1] };
    float r1f[2] = { rel1[0], rel1[1] };
    if (flip3 == 1)      { r1f[0] = -r1f[0]; r1f[1] = -r1f[1]; }
    else if (flip3 == 2) { r0f[0] = -r0f[0]; r0f[1] = -r0f[1]; }
    else if (flip3 == 4) { r0f[0] = -r0f[0]; r0f[1] = -r0f[1];
                           r1f[0] = -r1f[0]; r1f[1] = -r1f[1]; }

    float ex[2][7], ey[2][7];
    embed7(r0f[0], ex[0]); embed7(r0f[1], ex[1]);
    embed7(r1f[0], ey[0]); embed7(r1f[1], ey[1]);

    float acc0 = 0.0f, acc1 = 0.0f, acc2 = 0.0f;

    #pragma unroll
    for (int s = 0; s < 4; ++s) {
        const int dx = s >> 1;
        const int dy = s & 1;
        const float4* __restrict__ bp =
            (const float4*)(&lds[(size_t)dx * (FW * CST) + (size_t)iwy[dy] * CST]);

        // 49 outer-product weights (static regs)
        float wv[49];
        #pragma unroll
        for (int a = 0; a < 7; ++a) {
            const float ea = ex[dx][a];
            #pragma unroll
            for (int b = 0; b < 7; ++b) wv[a * 7 + b] = ea * ey[dy][b];
        }

        float p0 = 0.0f, p1 = 0.0f, p2 = 0.0f;
        #pragma unroll
        for (int g = 0; g < NG; ++g) {
            float4 v = bp[g];
            const int c0 = 4 * g;
            {   // e = 0..3, all indices fold to constants after unroll
                #define ACCUM(C, VAL)                                          \
                    if ((C) < 49)       p0 = fmaf(wv[(C)],      (VAL), p0);    \
                    else if ((C) < 98)  p1 = fmaf(wv[(C) - 49], (VAL), p1);    \
                    else if ((C) < 147) p2 = fmaf(wv[(C) - 98], (VAL), p2);
                ACCUM(c0 + 0, v.x)
                ACCUM(c0 + 1, v.y)
                ACCUM(c0 + 2, v.z)
                ACCUM(c0 + 3, v.w)
                #undef ACCUM
            }
        }
        const float w = wgt[s];
        acc0 = fmaf(p0, w, acc0);
        acc1 = fmaf(p1, w, acc1);
        acc2 = fmaf(p2, w, acc2);
    }

    const size_t ob = (size_t)n * 3 * OH * OW + (size_t)i * OW + (size_t)tid;
    out[ob              ] = acc0;
    out[ob +     OH * OW] = acc1;
    out[ob + 2 * OH * OW] = acc2;
}

extern "C" void kernel_launch(void* const* d_in, const int* in_sizes, int n_in,
                              void* d_out, int out_size, void* d_ws, size_t ws_size,
                              hipStream_t stream) {
    const float* feat  = (const float*)d_in[0];
    const int*   flip1 = (const int*)d_in[3];
    const int*   flip3 = (const int*)d_in[4];
    float*       out   = (float*)d_out;

    dim3 grid(1024);    // flattened (n,i), XCD-swizzled in-kernel
    dim3 block(OW);
    hipLaunchKernelGGL(ope_render_kernel, grid, block, 0, stream,
                       feat, flip1, flip3, out);
}

// Round 4
// 14.299 us; speedup vs baseline: 11.6671x; 1.9479x over previous
//
#include <hip/hip_runtime.h>
#include <math.h>

// feat: (N=4, C3=147, H=64, W=64) fp32 ; out: (4, 3, 256, 256) fp32
// Grouping theorem (exact fp32): for output idx t, nearest-sample indices
// (both corner shifts) are constant over t in {4q+2..4q+5}; boundary groups
// {0,1} (both corners -> 0) and {254,255} (both -> 63). Flips are exact
// negations -> index reversal, preserving the group structure.

#define FH 64
#define FW 64
#define NC3 147
#define OHW 256
#define CPAD 52          // 49 ch padded to 13 float4; 13 quads (odd) -> conflict-free
#define LDSZ (2 * FW * CPAD)   // 26624 B

__device__ __forceinline__ void embed7(float r, float e[7]) {
    const float F1  = 1.5707963705062866f;  // float32(0.5*pi)
    const float SQ2 = 1.4142135381698608f;  // float32(sqrt(2))
    float a = r * F1;
    float s1 = __sinf(a), c1 = __cosf(a);
    float s2 = 2.0f * s1 * c1, c2 = c1 * c1 - s1 * s1;
    float s3 = s2 * c1 + c2 * s1, c3 = c2 * c1 - s2 * s1;
    e[0] = 1.0f;
    e[1] = SQ2 * c1; e[2] = SQ2 * s1;
    e[3] = SQ2 * c2; e[4] = SQ2 * s2;
    e[5] = SQ2 * c3; e[6] = SQ2 * s3;
}

// block = (k, i-group, n); thread = (i-member m = tid>>6, j-group jg = tid&63)
// each thread computes 4 output pixels (its j-group) for one (n, i, k).
__global__ __launch_bounds__(256, 2) void ope_render_kernel(
    const float* __restrict__ feat,
    const int* __restrict__ pflip1,
    const int* __restrict__ pflip3,
    float* __restrict__ out)
{
    __shared__ float lds[LDSZ];   // [rowHalf(2)][col(64)][CPAD]

    const int tid = threadIdx.x;
    const int k   = blockIdx.x;   // 0..2 (output channel = 49-ch slice)
    const int ib  = blockIdx.y;   // 0..63 (i-group; ib==0 merged {0,1,254,255})
    const int n   = blockIdx.z;   // 0..3
    const int flip1 = pflip1[0];
    const int flip3 = pflip3[0];

    const int rA = (ib == 0) ? 0  : (ib - 1);
    const int rB = (ib == 0) ? 63 : ib;

    // ---- stage: 2 rows x 64 cols x 49 ch (padded 52) of channel slice k ----
    {
        const int cbase = k * 49;
        #pragma unroll
        for (int it = 0; it < 7; ++it) {
            int u = tid + it * 256;                 // u = (g*2 + d)*64 + col
            if (u < 2 * 13 * FW) {
                int col = u & 63;
                int d   = (u >> 6) & 1;
                int g   = u >> 7;                   // 0..12
                int row = d ? rB : rA;
                int c0  = cbase + 4 * g;
                const float* __restrict__ src =
                    feat + (((size_t)n * NC3 + c0) * FH + row) * FW + col;
                float4 v;
                v.x = src[0];
                v.y = (4 * g + 1 < 49) ? src[FH * FW]     : 0.0f;
                v.z = (4 * g + 2 < 49) ? src[2 * FH * FW] : 0.0f;
                v.w = (4 * g + 3 < 49) ? src[3 * FH * FW] : 0.0f;
                *(float4*)&lds[(size_t)((d << 6) + col) * CPAD + 4 * g] = v;
            }
        }
    }
    __syncthreads();

    const int m  = tid >> 6;      // i-member 0..3 (uniform per wave)
    const int jg = tid & 63;      // j-group lane
    const bool fx = (flip1 == 2) || (flip1 == 4);
    const bool fy = (flip1 == 1) || (flip1 == 4);

    const float SHm = (float)(-1.0 / 64.0 + 1e-6);
    const float SHp = (float)( 1.0 / 64.0 + 1e-6);
    const float CLO = (float)(-1.0 + 1e-6);
    const float CHI = (float)( 1.0 - 1e-6);

    // effective (unflipped) i index
    const int i_e = (ib == 0) ? ((m < 2) ? m : 252 + m) : (4 * ib - 2 + m);
    const float cx = -1.0f + (2.0f * (float)i_e + 1.0f) * (1.0f / 256.0f);

    float rel0[2]; int rl[2];
    #pragma unroll
    for (int dx = 0; dx < 2; ++dx) {
        float sh = dx ? SHp : SHm;
        float c0 = fminf(fmaxf(cx + sh, CLO), CHI);
        int ih = (int)rintf(((c0 + 1.0f) * 64.0f - 1.0f) * 0.5f);
        ih = min(max(ih, 0), FH - 1);
        rl[dx] = (ih == rB) ? 1 : 0;      // proven: ih in {rA, rB}
        float qh = -1.0f + (2.0f * (float)ih + 1.0f) * (1.0f / 64.0f);
        rel0[dx] = (cx - qh) * 64.0f;
    }

    // flip3 applies to rel used for embedding only (areas use abs)
    float r0a = rel0[0], r0b = rel0[1];
    if (flip3 == 2 || flip3 == 4) { r0a = -r0a; r0b = -r0b; }
    float ex[2][7];
    embed7(r0a, ex[0]); embed7(r0b, ex[1]);

    const int colU0 = (jg == 0) ? 0  : (jg - 1);
    const int colU1 = (jg == 0) ? 63 : jg;

    // ---- 4 colvecs: cv[dx][cu][b] = sum_a ex[dx][a] * M(row rl[dx], col cu)[7a+b]
    float cv[2][2][7];
    #pragma unroll
    for (int dx = 0; dx < 2; ++dx) {
        #pragma unroll
        for (int cu = 0; cu < 2; ++cu) {
            const float4* __restrict__ vp = (const float4*)
                &lds[(size_t)((rl[dx] << 6) + (cu ? colU1 : colU0)) * CPAD];
            float mreg[52];
            #pragma unroll
            for (int g = 0; g < 13; ++g) {
                float4 t = vp[g];
                mreg[4*g] = t.x; mreg[4*g+1] = t.y; mreg[4*g+2] = t.z; mreg[4*g+3] = t.w;
            }
            #pragma unroll
            for (int b = 0; b < 7; ++b) {
                float s = ex[dx][0] * mreg[b];
                #pragma unroll
                for (int a = 1; a < 7; ++a) s = fmaf(ex[dx][a], mreg[7*a + b], s);
                cv[dx][cu][b] = s;
            }
        }
    }

    // ---- per-j: embeds, weights, 4-corner dots ----
    float acc0, acc1, acc2, acc3;
    #pragma unroll
    for (int jj = 0; jj < 4; ++jj) {
        int j_e = (jg == 0) ? ((jj < 2) ? jj : 252 + jj) : (4 * jg - 2 + jj);
        float cy = -1.0f + (2.0f * (float)j_e + 1.0f) * (1.0f / 256.0f);

        float rel1[2]; bool cs[2];
        #pragma unroll
        for (int dy = 0; dy < 2; ++dy) {
            float sh = dy ? SHp : SHm;
            float c1 = fminf(fmaxf(cy + sh, CLO), CHI);
            int iw = (int)rintf(((c1 + 1.0f) * 64.0f - 1.0f) * 0.5f);
            iw = min(max(iw, 0), FW - 1);
            cs[dy] = (iw == colU1);           // proven: iw in {colU0, colU1}
            float qw = -1.0f + (2.0f * (float)iw + 1.0f) * (1.0f / 64.0f);
            rel1[dy] = (cy - qw) * 64.0f;
        }

        float a00 = fabsf(rel0[0] * rel1[0]) + 1e-9f;
        float a01 = fabsf(rel0[0] * rel1[1]) + 1e-9f;
        float a10 = fabsf(rel0[1] * rel1[0]) + 1e-9f;
        float a11 = fabsf(rel0[1] * rel1[1]) + 1e-9f;
        float tot = ((a00 + a01) + a10) + a11;
        float rinv = 1.0f / tot;
        float w00 = a11 * rinv, w01 = a10 * rinv, w10 = a01 * rinv, w11 = a00 * rinv;

        float r1a = rel1[0], r1b = rel1[1];
        if (flip3 == 1 || flip3 == 4) { r1a = -r1a; r1b = -r1b; }
        float ey0[7], ey1[7];
        embed7(r1a, ey0); embed7(r1b, ey1);

        bool s0 = cs[0], s1 = cs[1];
        float v00 = 0.0f, v01 = 0.0f, v10 = 0.0f, v11 = 0.0f;
        #pragma unroll
        for (int b = 0; b < 7; ++b) {
            float e0 = ey0[b], e1 = ey1[b];
            float c00 = s0 ? cv[0][1][b] : cv[0][0][b];
            float c10 = s0 ? cv[1][1][b] : cv[1][0][b];
            float c01 = s1 ? cv[0][1][b] : cv[0][0][b];
            float c11 = s1 ? cv[1][1][b] : cv[1][0][b];
            v00 = fmaf(c00, e0, v00);
            v10 = fmaf(c10, e0, v10);
            v01 = fmaf(c01, e1, v01);
            v11 = fmaf(c11, e1, v11);
        }
        float r = fmaf(v00, w00, fmaf(v01, w01, fmaf(v10, w10, v11 * w11)));
        if (jj == 0) acc0 = r; else if (jj == 1) acc1 = r;
        else if (jj == 2) acc2 = r; else acc3 = r;
    }

    // ---- stores: two aligned float2 per thread ----
    const int i_out = fx ? (255 - i_e) : i_e;
    float* __restrict__ ob = out + (((size_t)n * 3 + k) * OHW + i_out) * OHW;
    const int jA = (jg == 0) ? 0   : (4 * jg - 2);   // j_e at jj=0
    const int jB = (jg == 0) ? 254 : (4 * jg);       // j_e at jj=2
    if (!fy) {
        *(float2*)&ob[jA] = make_float2(acc0, acc1);
        *(float2*)&ob[jB] = make_float2(acc2, acc3);
    } else {
        *(float2*)&ob[254 - jA] = make_float2(acc1, acc0);
        *(float2*)&ob[254 - jB] = make_float2(acc3, acc2);
    }
}

extern "C" void kernel_launch(void* const* d_in, const int* in_sizes, int n_in,
                              void* d_out, int out_size, void* d_ws, size_t ws_size,
                              hipStream_t stream) {
    const float* feat  = (const float*)d_in[0];
    const int*   flip1 = (const int*)d_in[3];
    const int*   flip3 = (const int*)d_in[4];
    float*       out   = (float*)d_out;

    dim3 grid(3, 64, 4);   // (k, i-group, n)
    dim3 block(256);
    hipLaunchKernelGGL(ope_render_kernel, grid, block, 0, stream,
                       feat, flip1, flip3, out);
}

// Round 5
// 11.935 us; speedup vs baseline: 13.9781x; 1.1981x over previous
//
#include <hip/hip_runtime.h>
#include <math.h>

// feat: (N=4, C3=147, H=64, W=64) fp32 ; out: (4, 3, 256, 256) fp32
// Grouping theorem (exact fp32): for output idx t, nearest-sample indices
// (both corner shifts) are constant over t in {4q+2..4q+5} (interior), and
// constant over each PAIR {2p,2p+1} at the merged boundary group {0,1,254,255}.
// ex (h-axis embed) is wave-uniform -> lane-local column contraction + shuffle.

#define FH 64
#define FW 64
#define NC3 147
#define OHW 256
#define CPAD 52          // 49 ch padded to 13 float4; stride 52 -> conflict-free
#define LDSZ (2 * FW * CPAD)   // 26624 B

__device__ __forceinline__ void embed7(float r, float e[7]) {
    const float F1  = 1.5707963705062866f;  // float32(0.5*pi)
    const float SQ2 = 1.4142135381698608f;  // float32(sqrt(2))
    float a = r * F1;
    float s1 = __sinf(a), c1 = __cosf(a);
    float s2 = 2.0f * s1 * c1, c2 = c1 * c1 - s1 * s1;
    float s3 = s2 * c1 + c2 * s1, c3 = c2 * c1 - s2 * s1;
    e[0] = 1.0f;
    e[1] = SQ2 * c1; e[2] = SQ2 * s1;
    e[3] = SQ2 * c2; e[4] = SQ2 * s2;
    e[5] = SQ2 * c3; e[6] = SQ2 * s3;
}

// block = (k, i-group, n); wave = i-member m; lane = j-group jg.
__global__ __launch_bounds__(256, 3) void ope_render_kernel(
    const float* __restrict__ feat,
    const int* __restrict__ pflip1,
    const int* __restrict__ pflip3,
    float* __restrict__ out)
{
    __shared__ float lds[LDSZ];   // [rowHalf(2)][col(64)][CPAD]

    const int tid = threadIdx.x;
    const int k   = blockIdx.x;   // 0..2
    const int ib  = blockIdx.y;   // 0..63 (ib==0 merged {0,1,254,255})
    const int n   = blockIdx.z;   // 0..3
    const int flip1 = pflip1[0];
    const int flip3 = pflip3[0];

    const int rA = (ib == 0) ? 0  : (ib - 1);
    const int rB = (ib == 0) ? 63 : ib;

    // ---- T14 async-stage: issue all global loads first ----
    float4 sv[7];
    {
        const int cbase = k * 49;
        #pragma unroll
        for (int it = 0; it < 7; ++it) {
            int u = tid + it * 256;                 // u = (g*2 + d)*64 + col
            if (u < 2 * 13 * FW) {
                int col = u & 63;
                int d   = (u >> 6) & 1;
                int g   = u >> 7;                   // 0..12
                int row = d ? rB : rA;
                const float* __restrict__ src =
                    feat + (((size_t)n * NC3 + cbase + 4 * g) * FH + row) * FW + col;
                float4 v;
                v.x = src[0];
                v.y = (4 * g + 1 < 49) ? src[FH * FW]     : 0.0f;
                v.z = (4 * g + 2 < 49) ? src[2 * FH * FW] : 0.0f;
                v.w = (4 * g + 3 < 49) ? src[3 * FH * FW] : 0.0f;
                sv[it] = v;
            }
        }
    }

    // ---- coord / embed math overlaps load latency ----
    const int m  = tid >> 6;      // wave id = i-member
    const int jg = tid & 63;      // lane = j-group
    const bool fx = (flip1 == 2) || (flip1 == 4);
    const bool fy = (flip1 == 1) || (flip1 == 4);
    const bool o  = (jg == 0);

    const float SHm = (float)(-1.0 / 64.0 + 1e-6);
    const float SHp = (float)( 1.0 / 64.0 + 1e-6);
    const float CLO = (float)(-1.0 + 1e-6);
    const float CHI = (float)( 1.0 - 1e-6);

    const int i_e = (ib == 0) ? ((m < 2) ? m : 252 + m) : (4 * ib - 2 + m);
    const float cx = -1.0f + (2.0f * (float)i_e + 1.0f) * (1.0f / 256.0f);

    float rel0[2]; int rl[2];
    #pragma unroll
    for (int dx = 0; dx < 2; ++dx) {
        float sh = dx ? SHp : SHm;
        float c0 = fminf(fmaxf(cx + sh, CLO), CHI);
        int ih = (int)rintf(((c0 + 1.0f) * 64.0f - 1.0f) * 0.5f);
        ih = min(max(ih, 0), FH - 1);
        rl[dx] = (ih == rB) ? 1 : 0;      // proven: ih in {rA, rB}
        float qh = -1.0f + (2.0f * (float)ih + 1.0f) * (1.0f / 64.0f);
        rel0[dx] = (cx - qh) * 64.0f;
    }

    float r0a = rel0[0], r0b = rel0[1];
    if (flip3 == 2 || flip3 == 4) { r0a = -r0a; r0b = -r0b; }
    float ex[2][7];
    embed7(r0a, ex[0]); embed7(r0b, ex[1]);

    // ---- write staged data, barrier ----
    {
        #pragma unroll
        for (int it = 0; it < 7; ++it) {
            int u = tid + it * 256;
            if (u < 2 * 13 * FW) {
                int col = u & 63;
                int d   = (u >> 6) & 1;
                int g   = u >> 7;
                *(float4*)&lds[(size_t)((d << 6) + col) * CPAD + 4 * g] = sv[it];
            }
        }
    }
    __syncthreads();

    // ---- lane-local column contraction: tp[dx][b] for OWN col jg ----
    float tp[2][7];
    #pragma unroll
    for (int dx = 0; dx < 2; ++dx) {
        const float4* __restrict__ vp =
            (const float4*)&lds[(size_t)((rl[dx] << 6) + jg) * CPAD];
        float mreg[52];
        #pragma unroll
        for (int g = 0; g < 13; ++g) {
            float4 t = vp[g];
            mreg[4*g] = t.x; mreg[4*g+1] = t.y; mreg[4*g+2] = t.z; mreg[4*g+3] = t.w;
        }
        #pragma unroll
        for (int b = 0; b < 7; ++b) {
            float s = ex[dx][0] * mreg[b];
            #pragma unroll
            for (int a = 1; a < 7; ++a) s = fmaf(ex[dx][a], mreg[7*a + b], s);
            tp[dx][b] = s;
        }
    }

    // ---- neighbor-column results via shuffle (lane (jg-1)&63) ----
    const int srcl = (jg + 63) & 63;
    float qv[2][7];
    #pragma unroll
    for (int dx = 0; dx < 2; ++dx)
        #pragma unroll
        for (int b = 0; b < 7; ++b)
            qv[dx][b] = __shfl(tp[dx][b], srcl, 64);

    // ---- per-pair: hoisted iw/qw/cs + selection; per-sub: embeds + dots ----
    const int colU1 = o ? 63 : jg;
    float acc0, acc1, acc2, acc3;
    #pragma unroll
    for (int p = 0; p < 2; ++p) {
        const int jb = o ? (p ? 254 : 0) : (4 * jg - 2 + 2 * p);
        const float cyp = -1.0f + (2.0f * (float)jb + 1.0f) * (1.0f / 256.0f);
        float qw[2]; bool cs[2];
        #pragma unroll
        for (int dy = 0; dy < 2; ++dy) {
            float sh = dy ? SHp : SHm;
            float c1 = fminf(fmaxf(cyp + sh, CLO), CHI);
            int iw = (int)rintf(((c1 + 1.0f) * 64.0f - 1.0f) * 0.5f);
            iw = min(max(iw, 0), FW - 1);
            cs[dy] = (iw == colU1);
            qw[dy] = -1.0f + (2.0f * (float)iw + 1.0f) * (1.0f / 64.0f);
        }
        // cvs[dy][dx][b]: (cs^o) ? own-col tp : neighbor qv
        float cvs[2][2][7];
        #pragma unroll
        for (int dy = 0; dy < 2; ++dy) {
            const bool selP = cs[dy] != o;
            #pragma unroll
            for (int dx = 0; dx < 2; ++dx)
                #pragma unroll
                for (int b = 0; b < 7; ++b)
                    cvs[dy][dx][b] = selP ? tp[dx][b] : qv[dx][b];
        }
        #pragma unroll
        for (int sub = 0; sub < 2; ++sub) {
            const int j_e = jb + sub;
            const float cy = -1.0f + (2.0f * (float)j_e + 1.0f) * (1.0f / 256.0f);
            float rel1_0 = (cy - qw[0]) * 64.0f;
            float rel1_1 = (cy - qw[1]) * 64.0f;

            float a00 = fabsf(rel0[0] * rel1_0) + 1e-9f;
            float a01 = fabsf(rel0[0] * rel1_1) + 1e-9f;
            float a10 = fabsf(rel0[1] * rel1_0) + 1e-9f;
            float a11 = fabsf(rel0[1] * rel1_1) + 1e-9f;
            float tot = ((a00 + a01) + a10) + a11;
            float rinv = 1.0f / tot;
            float w00 = a11 * rinv, w01 = a10 * rinv, w10 = a01 * rinv, w11 = a00 * rinv;

            float r1a = rel1_0, r1b = rel1_1;
            if (flip3 == 1 || flip3 == 4) { r1a = -r1a; r1b = -r1b; }
            float ey0[7], ey1[7];
            embed7(r1a, ey0); embed7(r1b, ey1);

            float v00 = 0.0f, v01 = 0.0f, v10 = 0.0f, v11 = 0.0f;
            #pragma unroll
            for (int b = 0; b < 7; ++b) {
                v00 = fmaf(cvs[0][0][b], ey0[b], v00);
                v10 = fmaf(cvs[0][1][b], ey0[b], v10);
                v01 = fmaf(cvs[1][0][b], ey1[b], v01);
                v11 = fmaf(cvs[1][1][b], ey1[b], v11);
            }
            float r = fmaf(v00, w00, fmaf(v01, w01, fmaf(v10, w10, v11 * w11)));
            if (p == 0) { if (sub == 0) acc0 = r; else acc1 = r; }
            else        { if (sub == 0) acc2 = r; else acc3 = r; }
        }
    }

    // ---- stores: two aligned float2 per thread ----
    const int i_out = fx ? (255 - i_e) : i_e;
    float* __restrict__ ob = out + (((size_t)n * 3 + k) * OHW + i_out) * OHW;
    const int jA = o ? 0   : (4 * jg - 2);
    const int jB = o ? 254 : (4 * jg);
    if (!fy) {
        *(float2*)&ob[jA] = make_float2(acc0, acc1);
        *(float2*)&ob[jB] = make_float2(acc2, acc3);
    } else {
        *(float2*)&ob[254 - jA] = make_float2(acc1, acc0);
        *(float2*)&ob[254 - jB] = make_float2(acc3, acc2);
    }
}

extern "C" void kernel_launch(void* const* d_in, const int* in_sizes, int n_in,
                              void* d_out, int out_size, void* d_ws, size_t ws_size,
                              hipStream_t stream) {
    const float* feat  = (const float*)d_in[0];
    const int*   flip1 = (const int*)d_in[3];
    const int*   flip3 = (const int*)d_in[4];
    float*       out   = (float*)d_out;

    dim3 grid(3, 64, 4);   // (k, i-group, n)
    dim3 block(256);
    hipLaunchKernelGGL(ope_render_kernel, grid, block, 0, stream,
                       feat, flip1, flip3, out);
}